// Round 1
// baseline (506.122 us; speedup 1.0000x reference)
//
#include <hip/hip_runtime.h>
#include <hip/hip_bf16.h>

// ---------------------------------------------------------------------------
// AttentionMIL: x[16,4096,1024] -> Linear+LN+ReLU -> Linear+LN+ReLU ->
//               attention (tanh linear -> scalar -> softmax over N) ->
//               weighted pool -> 2-layer classifier -> logits [16,2]
// ---------------------------------------------------------------------------

#define MTOT   65536      // B*N rows
#define DDIM   1024
#define HDIM   512
#define NBAG   16
#define NINST  4096

typedef __attribute__((ext_vector_type(8))) short bf16x8;
typedef __attribute__((ext_vector_type(4))) float f32x4;

__device__ __forceinline__ unsigned short f2bf(float f) {
  __hip_bfloat16 h = __float2bfloat16(f);
  unsigned short u;
  __builtin_memcpy(&u, &h, 2);
  return u;
}
__device__ __forceinline__ float bf2f(unsigned short u) {
  unsigned int x = ((unsigned int)u) << 16;
  float f;
  __builtin_memcpy(&f, &x, 4);
  return f;
}

// ---------------------------------------------------------------------------
// transpose + cast f32 [R][C] -> bf16 [C][R]
// ---------------------------------------------------------------------------
__global__ void transpose_cast(const float* __restrict__ src,
                               __hip_bfloat16* __restrict__ dst,
                               int R, int C) {
  __shared__ float t[32][33];
  const int c0 = blockIdx.x * 32, r0 = blockIdx.y * 32;
  const int tx = threadIdx.x, ty = threadIdx.y;  // 32 x 8
#pragma unroll
  for (int i = 0; i < 32; i += 8)
    t[ty + i][tx] = src[(size_t)(r0 + ty + i) * C + c0 + tx];
  __syncthreads();
#pragma unroll
  for (int i = 0; i < 32; i += 8)
    dst[(size_t)(c0 + ty + i) * R + r0 + tx] = __float2bfloat16(t[tx][ty + i]);
}

// ---------------------------------------------------------------------------
// Fused GEMM:  out = A[M x KD] * BT^T   (BT is [512][KD] row-major = W^T)
// MODE 0: epilogue  relu(LN(y + bias, g, b))  -> bf16 out  (full 512-row LN)
// MODE 1: epilogue  score = sum_col tanh(y + bias) * wa2[col] + ba2 -> f32
// Block tile 64 x 512 (full width), 8 waves (2M x 4N), wave tile 32 x 128.
// ---------------------------------------------------------------------------
#define BM 64
#define BK 32
#define LDT (BK + 8)   // pad: 40 bf16 = 80B keeps 16B align, breaks bank stride

template <int KD, bool AF32, int MODE>
__global__ __launch_bounds__(512)
void gemm_fused(const void* Ap, const __hip_bfloat16* __restrict__ BT,
                const float* __restrict__ bias, const float* __restrict__ gg,
                const float* __restrict__ bb, const float* __restrict__ wa2,
                const float* __restrict__ ba2, __hip_bfloat16* outh,
                float* __restrict__ outs) {
  __shared__ __hip_bfloat16 At[BM][LDT];
  __shared__ __hip_bfloat16 Bt[HDIM][LDT];
  __shared__ float redS[BM][4];
  __shared__ float redQ[BM][4];
  __shared__ float muL[BM];
  __shared__ float rsL[BM];

  const int tid = threadIdx.x;
  const int lane = tid & 63;
  const int w = tid >> 6;
  const int wm = w >> 2;        // 0..1
  const int wn = w & 3;         // 0..3
  const int l16 = lane & 15;
  const int lg = lane >> 4;     // 0..3
  const size_t row0 = (size_t)blockIdx.x * BM;

  f32x4 acc[2][8];
#pragma unroll
  for (int i = 0; i < 2; i++)
#pragma unroll
    for (int j = 0; j < 8; j++) acc[i][j] = (f32x4){0.f, 0.f, 0.f, 0.f};

  const int ar = tid >> 3, ac4 = (tid & 7) * 4;   // f32 A staging
  const int ar2 = tid >> 2, ac8 = (tid & 3) * 8;  // bf16 A staging (tid<256)

  for (int kb = 0; kb < KD; kb += BK) {
    if (AF32) {
      const float* A = (const float*)Ap;
      float4 v = *reinterpret_cast<const float4*>(A + (row0 + ar) * KD + kb + ac4);
      ushort4 u;
      u.x = f2bf(v.x); u.y = f2bf(v.y); u.z = f2bf(v.z); u.w = f2bf(v.w);
      *reinterpret_cast<ushort4*>(&At[ar][ac4]) = u;
    } else {
      if (tid < 256) {
        const __hip_bfloat16* A = (const __hip_bfloat16*)Ap;
        int4 v = *reinterpret_cast<const int4*>(A + (row0 + ar2) * KD + kb + ac8);
        *reinterpret_cast<int4*>(&At[ar2][ac8]) = v;
      }
    }
    {
      const __hip_bfloat16* src = BT + (size_t)tid * KD + kb;
      int4 v0 = reinterpret_cast<const int4*>(src)[0];
      int4 v1 = reinterpret_cast<const int4*>(src)[1];
      int4 v2 = reinterpret_cast<const int4*>(src)[2];
      int4 v3 = reinterpret_cast<const int4*>(src)[3];
      *reinterpret_cast<int4*>(&Bt[tid][0]) = v0;
      *reinterpret_cast<int4*>(&Bt[tid][8]) = v1;
      *reinterpret_cast<int4*>(&Bt[tid][16]) = v2;
      *reinterpret_cast<int4*>(&Bt[tid][24]) = v3;
    }
    __syncthreads();

    bf16x8 af[2], bfr[8];
#pragma unroll
    for (int fm = 0; fm < 2; fm++)
      af[fm] = *reinterpret_cast<const bf16x8*>(&At[wm * 32 + fm * 16 + l16][lg * 8]);
#pragma unroll
    for (int fn = 0; fn < 8; fn++)
      bfr[fn] = *reinterpret_cast<const bf16x8*>(&Bt[wn * 128 + fn * 16 + l16][lg * 8]);
#pragma unroll
    for (int fm = 0; fm < 2; fm++)
#pragma unroll
      for (int fn = 0; fn < 8; fn++)
        acc[fm][fn] = __builtin_amdgcn_mfma_f32_16x16x32_bf16(af[fm], bfr[fn],
                                                              acc[fm][fn], 0, 0, 0);
    __syncthreads();
  }

  // ---------------- epilogue ----------------
  float biasv[8];
#pragma unroll
  for (int fn = 0; fn < 8; fn++) biasv[fn] = bias[wn * 128 + fn * 16 + l16];

  if (MODE == 0) {
    float gv[8], bv[8];
#pragma unroll
    for (int fn = 0; fn < 8; fn++) {
      const int col = wn * 128 + fn * 16 + l16;
      gv[fn] = gg[col];
      bv[fn] = bb[col];
    }
#pragma unroll
    for (int fm = 0; fm < 2; fm++)
#pragma unroll
      for (int r = 0; r < 4; r++) {
        float s1 = 0.f, s2 = 0.f;
#pragma unroll
        for (int fn = 0; fn < 8; fn++) {
          const float v = acc[fm][fn][r] + biasv[fn];
          s1 += v;
          s2 += v * v;
        }
#pragma unroll
        for (int m = 1; m < 16; m <<= 1) {
          s1 += __shfl_xor(s1, m);
          s2 += __shfl_xor(s2, m);
        }
        if (l16 == 0) {
          const int rl = wm * 32 + fm * 16 + lg * 4 + r;
          redS[rl][wn] = s1;
          redQ[rl][wn] = s2;
        }
      }
    __syncthreads();
    if (tid < BM) {
      const float S = redS[tid][0] + redS[tid][1] + redS[tid][2] + redS[tid][3];
      const float Q = redQ[tid][0] + redQ[tid][1] + redQ[tid][2] + redQ[tid][3];
      const float mean = S * (1.f / 512.f);
      const float var = Q * (1.f / 512.f) - mean * mean;
      muL[tid] = mean;
      rsL[tid] = rsqrtf(var + 1e-5f);
    }
    __syncthreads();
#pragma unroll
    for (int fm = 0; fm < 2; fm++)
#pragma unroll
      for (int r = 0; r < 4; r++) {
        const int rl = wm * 32 + fm * 16 + lg * 4 + r;
        const float mu = muL[rl], rs = rsL[rl];
#pragma unroll
        for (int fn = 0; fn < 8; fn++) {
          const float v = acc[fm][fn][r] + biasv[fn];
          float y = (v - mu) * rs * gv[fn] + bv[fn];
          y = fmaxf(y, 0.f);
          outh[(row0 + rl) * HDIM + wn * 128 + fn * 16 + l16] = __float2bfloat16(y);
        }
      }
  } else {
    float wv[8];
#pragma unroll
    for (int fn = 0; fn < 8; fn++) wv[fn] = wa2[wn * 128 + fn * 16 + l16];
#pragma unroll
    for (int fm = 0; fm < 2; fm++)
#pragma unroll
      for (int r = 0; r < 4; r++) {
        float s = 0.f;
#pragma unroll
        for (int fn = 0; fn < 8; fn++) {
          const float v = acc[fm][fn][r] + biasv[fn];
          s += tanhf(v) * wv[fn];
        }
#pragma unroll
        for (int m = 1; m < 16; m <<= 1) s += __shfl_xor(s, m);
        if (l16 == 0) redS[wm * 32 + fm * 16 + lg * 4 + r][wn] = s;
      }
    __syncthreads();
    if (tid < BM) {
      const float sc =
          redS[tid][0] + redS[tid][1] + redS[tid][2] + redS[tid][3] + ba2[0];
      outs[row0 + tid] = sc;
    }
  }
}

// ---------------------------------------------------------------------------
// softmax over 4096 instances per bag (16 blocks)
// ---------------------------------------------------------------------------
__global__ void softmax_bag(const float* __restrict__ sc, float* __restrict__ at) {
  const int b = blockIdx.x;
  const int tid = threadIdx.x;  // 256
  const int lane = tid & 63, w = tid >> 6;
  const float* s = sc + (size_t)b * NINST;
  float v[16];
  float mx = -1e30f;
#pragma unroll
  for (int i = 0; i < 16; i++) {
    v[i] = s[tid + i * 256];
    mx = fmaxf(mx, v[i]);
  }
#pragma unroll
  for (int off = 32; off; off >>= 1) mx = fmaxf(mx, __shfl_xor(mx, off));
  __shared__ float red[4];
  if (lane == 0) red[w] = mx;
  __syncthreads();
  mx = fmaxf(fmaxf(red[0], red[1]), fmaxf(red[2], red[3]));
  float sum = 0.f;
#pragma unroll
  for (int i = 0; i < 16; i++) {
    v[i] = expf(v[i] - mx);
    sum += v[i];
  }
#pragma unroll
  for (int off = 32; off; off >>= 1) sum += __shfl_xor(sum, off);
  __shared__ float red2[4];
  if (lane == 0) red2[w] = sum;
  __syncthreads();
  sum = red2[0] + red2[1] + red2[2] + red2[3];
  const float inv = 1.f / sum;
#pragma unroll
  for (int i = 0; i < 16; i++) at[(size_t)b * NINST + tid + i * 256] = v[i] * inv;
}

// ---------------------------------------------------------------------------
// pooled[b,h] = sum_n attn[b,n] * h2[b,n,h]   (two-stage, no atomics)
// grid 512: b = bid>>5, cc = (bid>>3)&3, nch = bid&7
// ---------------------------------------------------------------------------
__global__ void pooled_partial(const __hip_bfloat16* __restrict__ h2,
                               const float* __restrict__ at,
                               float* __restrict__ part) {
  const int bid = blockIdx.x;
  const int b = bid >> 5, cc = (bid >> 3) & 3, nch = bid & 7;
  const int tid = threadIdx.x;  // 256
  const int c4 = (tid & 31) * 4, sub = tid >> 5;
  const int n0 = nch * 512;
  const size_t base = (size_t)b * NINST;
  float a0 = 0.f, a1 = 0.f, a2 = 0.f, a3 = 0.f;
  for (int n = n0 + sub; n < n0 + 512; n += 8) {
    const float a = at[base + n];
    const ushort4 u = *reinterpret_cast<const ushort4*>(
        &h2[(base + n) * HDIM + cc * 128 + c4]);
    a0 += a * bf2f(u.x);
    a1 += a * bf2f(u.y);
    a2 += a * bf2f(u.z);
    a3 += a * bf2f(u.w);
  }
  __shared__ float pb[8][128];
  pb[sub][c4 + 0] = a0;
  pb[sub][c4 + 1] = a1;
  pb[sub][c4 + 2] = a2;
  pb[sub][c4 + 3] = a3;
  __syncthreads();
  if (tid < 128) {
    float s = 0.f;
#pragma unroll
    for (int j = 0; j < 8; j++) s += pb[j][tid];
    part[(size_t)nch * 8192 + b * 512 + cc * 128 + tid] = s;
  }
}

__global__ void pooled_reduce(const float* __restrict__ part,
                              float* __restrict__ pooled) {
  const int i = blockIdx.x * 256 + threadIdx.x;  // 8192 total
  float s = 0.f;
#pragma unroll
  for (int j = 0; j < 8; j++) s += part[(size_t)j * 8192 + i];
  pooled[i] = s;
}

// ---------------------------------------------------------------------------
// classifier: logits = relu(pooled @ Wc1 + bc1) @ Wc2 + bc2   (1 block, f32)
// ---------------------------------------------------------------------------
__global__ void classifier(const float* __restrict__ pooled,
                           const float* __restrict__ Wc1,
                           const float* __restrict__ bc1,
                           const float* __restrict__ Wc2,
                           const float* __restrict__ bc2,
                           float* __restrict__ out) {
  __shared__ float P[NBAG][512];
  __shared__ float Rb[NBAG][512];
  const int tid = threadIdx.x;  // 512
#pragma unroll
  for (int i = 0; i < NBAG; i++) P[i][tid] = pooled[i * 512 + tid];
  __syncthreads();
  float r[NBAG];
#pragma unroll
  for (int i = 0; i < NBAG; i++) r[i] = 0.f;
  for (int k = 0; k < 512; k++) {
    const float wv = Wc1[k * 512 + tid];
#pragma unroll
    for (int i = 0; i < NBAG; i++) r[i] += P[i][k] * wv;
  }
#pragma unroll
  for (int i = 0; i < NBAG; i++) Rb[i][tid] = fmaxf(r[i] + bc1[tid], 0.f);
  __syncthreads();
  if (tid < 32) {
    const int i = tid >> 1, c = tid & 1;
    float s = bc2[c];
    for (int k = 0; k < 512; k++) s += Rb[i][k] * Wc2[k * 2 + c];
    out[i * 2 + c] = s;
  }
}

// ---------------------------------------------------------------------------
extern "C" void kernel_launch(void* const* d_in, const int* in_sizes, int n_in,
                              void* d_out, int out_size, void* d_ws,
                              size_t ws_size, hipStream_t stream) {
  const float* x   = (const float*)d_in[0];
  const float* W1  = (const float*)d_in[1];
  const float* b1  = (const float*)d_in[2];
  const float* g1  = (const float*)d_in[3];
  const float* be1 = (const float*)d_in[4];
  const float* W2  = (const float*)d_in[5];
  const float* b2  = (const float*)d_in[6];
  const float* g2  = (const float*)d_in[7];
  const float* be2 = (const float*)d_in[8];
  const float* Wa1 = (const float*)d_in[9];
  const float* ba1 = (const float*)d_in[10];
  const float* wa2 = (const float*)d_in[11];
  const float* ba2 = (const float*)d_in[12];
  const float* Wc1 = (const float*)d_in[13];
  const float* bc1 = (const float*)d_in[14];
  const float* Wc2 = (const float*)d_in[15];
  const float* bc2 = (const float*)d_in[16];
  float* out = (float*)d_out;

  char* ws = (char*)d_ws;
  __hip_bfloat16* W1T = (__hip_bfloat16*)(ws + 0);          // 1 MB
  __hip_bfloat16* W2T = (__hip_bfloat16*)(ws + 1048576);    // 512 KB
  __hip_bfloat16* WaT = (__hip_bfloat16*)(ws + 1572864);    // 512 KB
  float* scores = (float*)(ws + 2097152);                   // 256 KB
  float* attn   = (float*)(ws + 2359296);                   // 256 KB
  float* part   = (float*)(ws + 2621440);                   // 256 KB
  float* pooled = (float*)(ws + 2883584);                   // 32 KB
  __hip_bfloat16* hbuf = (__hip_bfloat16*)(ws + 4194304);   // 64 MB (h1/h2 alias)

  transpose_cast<<<dim3(16, 32), dim3(32, 8), 0, stream>>>(W1, W1T, DDIM, HDIM);
  transpose_cast<<<dim3(16, 16), dim3(32, 8), 0, stream>>>(W2, W2T, HDIM, HDIM);
  transpose_cast<<<dim3(16, 16), dim3(32, 8), 0, stream>>>(Wa1, WaT, HDIM, HDIM);

  // GEMM1: h1 = relu(LN(x @ W1 + b1))
  gemm_fused<DDIM, true, 0><<<MTOT / BM, 512, 0, stream>>>(
      x, W1T, b1, g1, be1, nullptr, nullptr, hbuf, nullptr);
  // GEMM2: h2 = relu(LN(h1 @ W2 + b2))   (in-place over h1: block-local rows)
  gemm_fused<HDIM, false, 0><<<MTOT / BM, 512, 0, stream>>>(
      hbuf, W2T, b2, g2, be2, nullptr, nullptr, hbuf, nullptr);
  // GEMM-attn: scores = tanh(h2 @ Wa1 + ba1) . wa2 + ba2
  gemm_fused<HDIM, false, 1><<<MTOT / BM, 512, 0, stream>>>(
      hbuf, WaT, ba1, nullptr, nullptr, wa2, ba2, nullptr, scores);

  softmax_bag<<<NBAG, 256, 0, stream>>>(scores, attn);
  pooled_partial<<<512, 256, 0, stream>>>(hbuf, attn, part);
  pooled_reduce<<<32, 256, 0, stream>>>(part, pooled);
  classifier<<<1, 512, 0, stream>>>(pooled, Wc1, bc1, Wc2, bc2, out);
}

// Round 2
// 386.525 us; speedup vs baseline: 1.3094x; 1.3094x over previous
//
#include <hip/hip_runtime.h>
#include <hip/hip_bf16.h>

// ---------------------------------------------------------------------------
// AttentionMIL: x[16,4096,1024] -> Linear+LN+ReLU -> Linear+LN+ReLU ->
//               attention (tanh linear -> scalar -> softmax over N) ->
//               weighted pool -> 2-layer classifier -> logits [16,2]
// ---------------------------------------------------------------------------

#define MTOT   65536
#define DDIM   1024
#define HDIM   512
#define NBAG   16
#define NINST  4096

typedef __attribute__((ext_vector_type(8))) short bf16x8;
typedef __attribute__((ext_vector_type(4))) float f32x4;

__device__ __forceinline__ unsigned short f2bf(float f) {
  __hip_bfloat16 h = __float2bfloat16(f);
  unsigned short u;
  __builtin_memcpy(&u, &h, 2);
  return u;
}
__device__ __forceinline__ float bf2f(unsigned short u) {
  unsigned int x = ((unsigned int)u) << 16;
  float f;
  __builtin_memcpy(&f, &x, 4);
  return f;
}

__device__ __forceinline__ void gload16(const void* g, void* l) {
  __builtin_amdgcn_global_load_lds(
      (const __attribute__((address_space(1))) unsigned int*)g,
      (__attribute__((address_space(3))) unsigned int*)l, 16, 0, 0);
}

__device__ __forceinline__ bf16x8 pack8(float4 a, float4 b) {
  bf16x8 r;
  r[0] = (short)f2bf(a.x); r[1] = (short)f2bf(a.y);
  r[2] = (short)f2bf(a.z); r[3] = (short)f2bf(a.w);
  r[4] = (short)f2bf(b.x); r[5] = (short)f2bf(b.y);
  r[6] = (short)f2bf(b.z); r[7] = (short)f2bf(b.w);
  return r;
}

// ---------------------------------------------------------------------------
// transpose + cast f32 [R][C] -> bf16 [C][R]
// ---------------------------------------------------------------------------
__global__ void transpose_cast(const float* __restrict__ src,
                               __hip_bfloat16* __restrict__ dst,
                               int R, int C) {
  __shared__ float t[32][33];
  const int c0 = blockIdx.x * 32, r0 = blockIdx.y * 32;
  const int tx = threadIdx.x, ty = threadIdx.y;  // 32 x 8
#pragma unroll
  for (int i = 0; i < 32; i += 8)
    t[ty + i][tx] = src[(size_t)(r0 + ty + i) * C + c0 + tx];
  __syncthreads();
#pragma unroll
  for (int i = 0; i < 32; i += 8)
    dst[(size_t)(c0 + ty + i) * R + r0 + tx] = __float2bfloat16(t[tx][ty + i]);
}

// ---------------------------------------------------------------------------
// Fused GEMM: out = A[M x KD] * BT^T    (BT = W^T, [512][KD] row-major)
// MODE 0: relu(LN(y+bias, g, b)) -> bf16      MODE 1: tanh(y+bias).wa2 -> f32
// Tile 128 x 512 (full width so LN fuses), BK=64, 8 waves (2M x 4N),
// wave tile 64x128 (fm=4, fn=8). A double-buffered (gload_lds or reg-cvt),
// B single-buffered gload_lds. XOR-swizzled LDS (slot ^= row&7, 16B slots).
// ---------------------------------------------------------------------------
#define BM 128
#define BK 64
#define NW 8

template <int KD, bool AF32, int MODE>
__global__ __launch_bounds__(512, 2)
void gemm_fused(const void* Ap, const __hip_bfloat16* __restrict__ BT,
                const float* __restrict__ bias, const float* __restrict__ gg,
                const float* __restrict__ bb, const float* __restrict__ wa2,
                const float* __restrict__ ba2, __hip_bfloat16* __restrict__ outh,
                float* __restrict__ outs) {
  __shared__ __hip_bfloat16 At[2][BM * BK];   // 2 x 16KB
  __shared__ __hip_bfloat16 Bt[HDIM * BK];    // 64KB
  __shared__ float redS[BM][4];
  __shared__ float redQ[BM][4];
  __shared__ float muL[BM];
  __shared__ float rsL[BM];

  const int tid  = threadIdx.x;
  const int lane = tid & 63;
  const int w    = tid >> 6;
  const int wm   = w >> 2;      // 0..1
  const int wn   = w & 3;       // 0..3
  const int l16  = lane & 15;
  const int lg   = lane >> 4;   // 0..3
  const size_t row0 = (size_t)blockIdx.x * BM;

  const int sr = tid >> 3;      // staging row sub-index (0..63)
  const int sp = tid & 7;       // physical 16B slot

  f32x4 acc[4][8];
#pragma unroll
  for (int i = 0; i < 4; i++)
#pragma unroll
    for (int j = 0; j < 8; j++) acc[i][j] = (f32x4){0.f, 0.f, 0.f, 0.f};

  const int NT = KD / BK;
  const __hip_bfloat16* Abf = (const __hip_bfloat16*)Ap;
  const float* Af32 = (const float*)Ap;

  // ---- staging helpers (inline lambdas) ----
  auto stageB = [&](int kb) {
#pragma unroll
    for (int i = 0; i < 8; i++) {
      const int row = i * 64 + sr;
      const int slog = sp ^ (row & 7);
      gload16(BT + (size_t)row * KD + kb + slog * 8, &Bt[row * BK + sp * 8]);
    }
  };
  auto stageA_lds = [&](int kb, int buf) {
#pragma unroll
    for (int j = 0; j < 2; j++) {
      const int row = j * 64 + sr;
      const int slog = sp ^ (row & 7);
      gload16(Abf + (row0 + row) * KD + kb + slog * 8,
              &At[buf][row * BK + sp * 8]);
    }
  };

  float4 fa[2][2];  // AF32 staged regs (2 slots x 8 f32)
  auto loadA_f32 = [&](int kb) {
#pragma unroll
    for (int j = 0; j < 2; j++) {
      const int row = j * 64 + sr;
      const int slog = sp ^ (row & 7);
      const float* gp = Af32 + (row0 + row) * KD + kb + slog * 8;
      fa[j][0] = *reinterpret_cast<const float4*>(gp);
      fa[j][1] = *reinterpret_cast<const float4*>(gp + 4);
    }
  };
  auto writeA_f32 = [&](int buf) {
#pragma unroll
    for (int j = 0; j < 2; j++) {
      const int row = j * 64 + sr;
      *reinterpret_cast<bf16x8*>(&At[buf][row * BK + sp * 8]) =
          pack8(fa[j][0], fa[j][1]);
    }
  };

  // ---- prologue: stage tile 0 ----
  if (AF32) {
    loadA_f32(0);
    writeA_f32(0);
  } else {
    stageA_lds(0, 0);
  }
  stageB(0);
  __syncthreads();

  int cur = 0;
  for (int t = 0; t < NT; ++t) {
    const int kb_next = (t + 1) * BK;
    if (t + 1 < NT) {
      if (AF32) loadA_f32(kb_next);          // issue to regs (drains @barrier1)
      else      stageA_lds(kb_next, cur ^ 1); // issue gload_lds
    }
    // ---- compute current tile ----
#pragma unroll
    for (int h = 0; h < 2; ++h) {
      bf16x8 af[4], bfr[8];
#pragma unroll
      for (int fm = 0; fm < 4; fm++) {
        const int row = wm * 64 + fm * 16 + l16;
        const int s = (h * 4 + lg) ^ (row & 7);
        af[fm] = *reinterpret_cast<const bf16x8*>(&At[cur][row * BK + s * 8]);
      }
#pragma unroll
      for (int fn = 0; fn < 8; fn++) {
        const int row = wn * 128 + fn * 16 + l16;
        const int s = (h * 4 + lg) ^ (row & 7);
        bfr[fn] = *reinterpret_cast<const bf16x8*>(&Bt[row * BK + s * 8]);
      }
#pragma unroll
      for (int fm = 0; fm < 4; fm++)
#pragma unroll
        for (int fn = 0; fn < 8; fn++)
          acc[fm][fn] = __builtin_amdgcn_mfma_f32_16x16x32_bf16(
              af[fm], bfr[fn], acc[fm][fn], 0, 0, 0);
    }
    __syncthreads();  // barrier1: Bt free to overwrite; drains A(t+1) vmem
    if (t + 1 < NT) {
      if (AF32) writeA_f32(cur ^ 1);
      stageB(kb_next);
    }
    __syncthreads();  // barrier2: B(t+1) + A ds_writes complete
    cur ^= 1;
  }

  // ---------------- epilogue ----------------
  float biasv[8];
#pragma unroll
  for (int fn = 0; fn < 8; fn++) biasv[fn] = bias[wn * 128 + fn * 16 + l16];

  if (MODE == 0) {
    float gv[8], bv[8];
#pragma unroll
    for (int fn = 0; fn < 8; fn++) {
      const int col = wn * 128 + fn * 16 + l16;
      gv[fn] = gg[col];
      bv[fn] = bb[col];
    }
#pragma unroll
    for (int fm = 0; fm < 4; fm++)
#pragma unroll
      for (int r = 0; r < 4; r++) {
        float s1 = 0.f, s2 = 0.f;
#pragma unroll
        for (int fn = 0; fn < 8; fn++) {
          const float v = acc[fm][fn][r] + biasv[fn];
          s1 += v;
          s2 += v * v;
        }
#pragma unroll
        for (int m = 1; m < 16; m <<= 1) {
          s1 += __shfl_xor(s1, m);
          s2 += __shfl_xor(s2, m);
        }
        if (l16 == 0) {
          const int rl = wm * 64 + fm * 16 + lg * 4 + r;
          redS[rl][wn] = s1;
          redQ[rl][wn] = s2;
        }
      }
    __syncthreads();
    if (tid < BM) {
      const float S = redS[tid][0] + redS[tid][1] + redS[tid][2] + redS[tid][3];
      const float Q = redQ[tid][0] + redQ[tid][1] + redQ[tid][2] + redQ[tid][3];
      const float mean = S * (1.f / 512.f);
      const float var = Q * (1.f / 512.f) - mean * mean;
      muL[tid] = mean;
      rsL[tid] = rsqrtf(var + 1e-5f);
    }
    __syncthreads();
#pragma unroll
    for (int fm = 0; fm < 4; fm++)
#pragma unroll
      for (int r = 0; r < 4; r++) {
        const int rl = wm * 64 + fm * 16 + lg * 4 + r;
        const float mu = muL[rl], rs = rsL[rl];
#pragma unroll
        for (int fn = 0; fn < 8; fn++) {
          const float v = acc[fm][fn][r] + biasv[fn];
          float y = (v - mu) * rs * gv[fn] + bv[fn];
          y = fmaxf(y, 0.f);
          outh[(row0 + rl) * HDIM + wn * 128 + fn * 16 + l16] =
              __float2bfloat16(y);
        }
      }
  } else {
    float wv[8];
#pragma unroll
    for (int fn = 0; fn < 8; fn++) wv[fn] = wa2[wn * 128 + fn * 16 + l16];
#pragma unroll
    for (int fm = 0; fm < 4; fm++)
#pragma unroll
      for (int r = 0; r < 4; r++) {
        float s = 0.f;
#pragma unroll
        for (int fn = 0; fn < 8; fn++) {
          const float v = acc[fm][fn][r] + biasv[fn];
          s += tanhf(v) * wv[fn];
        }
#pragma unroll
        for (int m = 1; m < 16; m <<= 1) s += __shfl_xor(s, m);
        if (l16 == 0) redS[wm * 64 + fm * 16 + lg * 4 + r][wn] = s;
      }
    __syncthreads();
    if (tid < BM) {
      outs[row0 + tid] =
          redS[tid][0] + redS[tid][1] + redS[tid][2] + redS[tid][3] + ba2[0];
    }
  }
}

// ---------------------------------------------------------------------------
// softmax over 4096 instances per bag
// ---------------------------------------------------------------------------
__global__ void softmax_bag(const float* __restrict__ sc, float* __restrict__ at) {
  const int b = blockIdx.x;
  const int tid = threadIdx.x;  // 256
  const int lane = tid & 63, w = tid >> 6;
  const float* s = sc + (size_t)b * NINST;
  float v[16];
  float mx = -1e30f;
#pragma unroll
  for (int i = 0; i < 16; i++) {
    v[i] = s[tid + i * 256];
    mx = fmaxf(mx, v[i]);
  }
#pragma unroll
  for (int off = 32; off; off >>= 1) mx = fmaxf(mx, __shfl_xor(mx, off));
  __shared__ float red[4];
  if (lane == 0) red[w] = mx;
  __syncthreads();
  mx = fmaxf(fmaxf(red[0], red[1]), fmaxf(red[2], red[3]));
  float sum = 0.f;
#pragma unroll
  for (int i = 0; i < 16; i++) {
    v[i] = expf(v[i] - mx);
    sum += v[i];
  }
#pragma unroll
  for (int off = 32; off; off >>= 1) sum += __shfl_xor(sum, off);
  __shared__ float red2[4];
  if (lane == 0) red2[w] = sum;
  __syncthreads();
  sum = red2[0] + red2[1] + red2[2] + red2[3];
  const float inv = 1.f / sum;
#pragma unroll
  for (int i = 0; i < 16; i++) at[(size_t)b * NINST + tid + i * 256] = v[i] * inv;
}

// ---------------------------------------------------------------------------
// pooled[b,h] = sum_n attn[b,n] * h2[b,n,h]
// ---------------------------------------------------------------------------
__global__ void pooled_partial(const __hip_bfloat16* __restrict__ h2,
                               const float* __restrict__ at,
                               float* __restrict__ part) {
  const int bid = blockIdx.x;
  const int b = bid >> 5, cc = (bid >> 3) & 3, nch = bid & 7;
  const int tid = threadIdx.x;  // 256
  const int c4 = (tid & 31) * 4, sub = tid >> 5;
  const int n0 = nch * 512;
  const size_t base = (size_t)b * NINST;
  float a0 = 0.f, a1 = 0.f, a2 = 0.f, a3 = 0.f;
  for (int n = n0 + sub; n < n0 + 512; n += 8) {
    const float a = at[base + n];
    const ushort4 u = *reinterpret_cast<const ushort4*>(
        &h2[(base + n) * HDIM + cc * 128 + c4]);
    a0 += a * bf2f(u.x);
    a1 += a * bf2f(u.y);
    a2 += a * bf2f(u.z);
    a3 += a * bf2f(u.w);
  }
  __shared__ float pb[8][128];
  pb[sub][c4 + 0] = a0;
  pb[sub][c4 + 1] = a1;
  pb[sub][c4 + 2] = a2;
  pb[sub][c4 + 3] = a3;
  __syncthreads();
  if (tid < 128) {
    float s = 0.f;
#pragma unroll
    for (int j = 0; j < 8; j++) s += pb[j][tid];
    part[(size_t)nch * 8192 + b * 512 + cc * 128 + tid] = s;
  }
}

__global__ void pooled_reduce(const float* __restrict__ part,
                              float* __restrict__ pooled) {
  const int i = blockIdx.x * 256 + threadIdx.x;  // 8192 total
  float s = 0.f;
#pragma unroll
  for (int j = 0; j < 8; j++) s += part[(size_t)j * 8192 + i];
  pooled[i] = s;
}

// ---------------------------------------------------------------------------
// classifier
// ---------------------------------------------------------------------------
__global__ void classifier(const float* __restrict__ pooled,
                           const float* __restrict__ Wc1,
                           const float* __restrict__ bc1,
                           const float* __restrict__ Wc2,
                           const float* __restrict__ bc2,
                           float* __restrict__ out) {
  __shared__ float P[NBAG][512];
  __shared__ float Rb[NBAG][512];
  const int tid = threadIdx.x;  // 512
#pragma unroll
  for (int i = 0; i < NBAG; i++) P[i][tid] = pooled[i * 512 + tid];
  __syncthreads();
  float r[NBAG];
#pragma unroll
  for (int i = 0; i < NBAG; i++) r[i] = 0.f;
  for (int k = 0; k < 512; k++) {
    const float wv = Wc1[k * 512 + tid];
#pragma unroll
    for (int i = 0; i < NBAG; i++) r[i] += P[i][k] * wv;
  }
#pragma unroll
  for (int i = 0; i < NBAG; i++) Rb[i][tid] = fmaxf(r[i] + bc1[tid], 0.f);
  __syncthreads();
  if (tid < 32) {
    const int i = tid >> 1, c = tid & 1;
    float s = bc2[c];
    for (int k = 0; k < 512; k++) s += Rb[i][k] * Wc2[k * 2 + c];
    out[i * 2 + c] = s;
  }
}

// ---------------------------------------------------------------------------
extern "C" void kernel_launch(void* const* d_in, const int* in_sizes, int n_in,
                              void* d_out, int out_size, void* d_ws,
                              size_t ws_size, hipStream_t stream) {
  const float* x   = (const float*)d_in[0];
  const float* W1  = (const float*)d_in[1];
  const float* b1  = (const float*)d_in[2];
  const float* g1  = (const float*)d_in[3];
  const float* be1 = (const float*)d_in[4];
  const float* W2  = (const float*)d_in[5];
  const float* b2  = (const float*)d_in[6];
  const float* g2  = (const float*)d_in[7];
  const float* be2 = (const float*)d_in[8];
  const float* Wa1 = (const float*)d_in[9];
  const float* ba1 = (const float*)d_in[10];
  const float* wa2 = (const float*)d_in[11];
  const float* ba2 = (const float*)d_in[12];
  const float* Wc1 = (const float*)d_in[13];
  const float* bc1 = (const float*)d_in[14];
  const float* Wc2 = (const float*)d_in[15];
  const float* bc2 = (const float*)d_in[16];
  float* out = (float*)d_out;

  char* ws = (char*)d_ws;
  __hip_bfloat16* W1T = (__hip_bfloat16*)(ws + 0);          // 1 MB
  __hip_bfloat16* W2T = (__hip_bfloat16*)(ws + 1048576);    // 512 KB
  __hip_bfloat16* WaT = (__hip_bfloat16*)(ws + 1572864);    // 512 KB
  float* scores = (float*)(ws + 2097152);                   // 256 KB
  float* attn   = (float*)(ws + 2359296);                   // 256 KB
  float* part   = (float*)(ws + 2621440);                   // 256 KB
  float* pooled = (float*)(ws + 2883584);                   // 32 KB
  __hip_bfloat16* hbuf = (__hip_bfloat16*)(ws + 4194304);   // 64 MB

  transpose_cast<<<dim3(16, 32), dim3(32, 8), 0, stream>>>(W1, W1T, DDIM, HDIM);
  transpose_cast<<<dim3(16, 16), dim3(32, 8), 0, stream>>>(W2, W2T, HDIM, HDIM);
  transpose_cast<<<dim3(16, 16), dim3(32, 8), 0, stream>>>(Wa1, WaT, HDIM, HDIM);

  gemm_fused<DDIM, true, 0><<<MTOT / BM, 512, 0, stream>>>(
      x, W1T, b1, g1, be1, nullptr, nullptr, hbuf, nullptr);
  gemm_fused<HDIM, false, 0><<<MTOT / BM, 512, 0, stream>>>(
      hbuf, W2T, b2, g2, be2, nullptr, nullptr, hbuf, nullptr);
  gemm_fused<HDIM, false, 1><<<MTOT / BM, 512, 0, stream>>>(
      hbuf, WaT, ba1, nullptr, nullptr, wa2, ba2, nullptr, scores);

  softmax_bag<<<NBAG, 256, 0, stream>>>(scores, attn);
  pooled_partial<<<512, 256, 0, stream>>>(hbuf, attn, part);
  pooled_reduce<<<32, 256, 0, stream>>>(part, pooled);
  classifier<<<1, 512, 0, stream>>>(pooled, Wc1, bc1, Wc2, bc2, out);
}